// Round 13
// baseline (366.634 us; speedup 1.0000x reference)
//
#include <hip/hip_runtime.h>
#include <math.h>

typedef _Float16 f16x8 __attribute__((ext_vector_type(8)));
typedef float f32x16 __attribute__((ext_vector_type(16)));
typedef unsigned int uint4v __attribute__((ext_vector_type(4)));

namespace {
constexpr int LDIM = 26;
constexpr int KDIM = 64;
constexpr int NSAMP = 262144;
constexpr int NITER = 8;
constexpr float WFLOOR = 1e-5f;
constexpr float VFLOOR = 1e-6f;
constexpr float LOG2PI_TERM = 47.784803726642976f;  // 26 * ln(2*pi)
constexpr float L2E = 1.44269504088896340736f;
constexpr float LN2 = 0.69314718055994530942f;

constexpr int ACC_STRIDE = 53;                       // z, px[26], pxx[26]
constexpr int ACC_N = KDIM * ACC_STRIDE + 1;         // 3393 (last = ll)
constexpr int NCOPIES = 8;
constexpr int WROW = 36;                             // dwords per coef row
constexpr int NBLK = 1024;                           // 2 indep waves/block; 256 samples/block
constexpr int PART_STRIDE = 3408;
constexpr int RED_BLK = 14;                          // reduce grid x (14*256 >= ACC_N)
}

// Static device storage (no dependence on the harness workspace; no fp atomics).
__device__ float g_partial[NBLK * PART_STRIDE];                         // ~14 MB
__device__ float g_accum[NCOPIES * ACC_N];                              // 108 KB
__device__ float g_w[KDIM];
__device__ float g_mu[KDIM * LDIM];
__device__ float g_sig[KDIM * LDIM];
__device__ float g_ll[1];
__device__ __align__(16) unsigned g_coef[KDIM * WROW];                  // f16-pair coef rows
__device__ int g_ticket;                                                // last-block election

__device__ __forceinline__ unsigned pkrtz(float a, float b) {
  return __builtin_bit_cast(unsigned, __builtin_amdgcn_cvt_pkrtz(a, b));
}
__device__ __forceinline__ f16x8 ld8h(const unsigned* p) {
  uint4v v = *(const uint4v*)p;
  return __builtin_bit_cast(f16x8, v);
}
__device__ __forceinline__ f32x16 mfma16(f16x8 a, f16x8 b, f32x16 c) {
  return __builtin_amdgcn_mfma_f32_32x32x16_f16(a, b, c, 0, 0, 0);
}
// async global->LDS DMA, 16B per lane
__device__ __forceinline__ void gload16(const void* g, void* l) {
  __builtin_amdgcn_global_load_lds(
      (const __attribute__((address_space(1))) unsigned*)g,
      (__attribute__((address_space(3))) unsigned*)l, 16, 0, 0);
}

// Coef row k (f16 pairs, 36-dword rows): slots 0..25 = -0.5/sig, 26..51 = mu/sig,
// 52 = C, 53 = C - f16(C) (split constant), rest 0.
__device__ void pack_row(int k, float w, const float* mu, const float* sg, unsigned* wp) {
  float A[LDIM], Bv[LDIM];
  float logdet = 0.f, q = 0.f;
#pragma unroll
  for (int l = 0; l < LDIM; ++l) {
    float pr = 1.0f / sg[l];
    logdet += __logf(sg[l]);
    A[l] = -0.5f * pr;
    Bv[l] = mu[l] * pr;
    q = __builtin_fmaf(mu[l] * mu[l], pr, q);
  }
  float C = __logf(w) - 0.5f * (LOG2PI_TERM + logdet + q);
  float Chi = (float)__builtin_amdgcn_cvt_pkrtz(C, 0.0f)[0];
  float Clo = C - Chi;
  unsigned* row = wp + k * WROW;
#define CF(f) ((f) < 26 ? A[(f)] : (f) < 52 ? Bv[(f) - 26] : (f) == 52 ? C : (f) == 53 ? Clo : 0.0f)
#pragma unroll
  for (int D = 0; D < 32; ++D) row[D] = pkrtz(CF(2 * D), CF(2 * D + 1));
#undef CF
#pragma unroll
  for (int D = 32; D < 36; ++D) row[D] = 0u;
}

__global__ void prep_coef(const float* __restrict__ w0, const float* __restrict__ mu0,
                          const float* __restrict__ sig0) {
  const int k = threadIdx.x;  // 64 threads
  float wv = w0[k];
  float s = wv;
#pragma unroll
  for (int d = 1; d < 64; d <<= 1) s += __shfl_xor(s, d, 64);
  float w = wv / s;
  float mu[LDIM], sg[LDIM];
#pragma unroll
  for (int l = 0; l < LDIM; ++l) {
    mu[l] = mu0[k * LDIM + l];
    sg[l] = sig0[k * LDIM + l];
  }
  pack_row(k, w, mu, sg, g_coef);
  if (k == 0) g_ticket = 0;
}

// R7 VERBATIM (the 301.5us verified kernel): 2 INDEPENDENT waves per block
// (128 threads), each processing 4 tiles of 32 samples with private LDS
// buffers — ZERO barriers in the main loop. Each wave holds BOTH k-halves;
// softmax over all 64 components is in-lane tree + one shfl_xor(32).
// Epilogue: barrier -> wave0 dumps accumulators into the LDS pool overlay
// (plain stores) -> barrier -> wave1 adds its own and writes the single block
// partial. The FIRST barrier is essential (R6's NaN race).
__global__ __launch_bounds__(128, 2) void em_mfma(const float* __restrict__ x) {
  // single pool hosting xtbuf+ptbuf, legally reusable as the reduce overlay
  __shared__ __align__(16) unsigned char pool[16384];
  __shared__ __align__(16) float stage[2][2][32 * LDIM];      // [warp][buf] 32x26 f32

  const int tid = threadIdx.x;
  const int lane = tid & 63;
  const int warp = tid >> 6;
  const int sl = lane & 31;
  const int h = lane >> 5;

  // layout: [warp][XT|SQT] at 0..8191, [warp][PT0|PT1] at 8192..16383
  unsigned short* XTs = (unsigned short*)&pool[warp * 4096];
  unsigned short* SQs = (unsigned short*)&pool[warp * 4096 + 2048];
  unsigned short* PT0s = (unsigned short*)&pool[8192 + warp * 4096];
  unsigned short* PT1s = (unsigned short*)&pool[8192 + warp * 4096 + 2048];
  const unsigned* XTd = (const unsigned*)XTs;
  const unsigned* SQd = (const unsigned*)SQs;
  const unsigned* PT0d = (const unsigned*)PT0s;
  const unsigned* PT1d = (const unsigned*)PT1s;

  f32x16 aX0 = {0,0,0,0,0,0,0,0,0,0,0,0,0,0,0,0};
  f32x16 aX1 = {0,0,0,0,0,0,0,0,0,0,0,0,0,0,0,0};
  f32x16 aQ0 = {0,0,0,0,0,0,0,0,0,0,0,0,0,0,0,0};
  f32x16 aQ1 = {0,0,0,0,0,0,0,0,0,0,0,0,0,0,0,0};
  float llacc = 0.f;

  const int sbase = blockIdx.x * 256 + warp * 128;
  const int rowbase0 = sl * WROW;
  const int rowbase1 = (32 + sl) * WROW;

  // ---- hoisted coefficient fragments for BOTH k-halves ----
  f16x8 ca00 = ld8h(g_coef + rowbase0 + 0 + 4 * h);
  f16x8 ca01 = ld8h(g_coef + rowbase0 + 8 + 4 * h);
  f16x8 ca02 = ld8h(g_coef + rowbase0 + 16 + 4 * h);
  f16x8 ca03 = ld8h(g_coef + rowbase0 + 24 + 4 * h);
  f16x8 ca10 = ld8h(g_coef + rowbase1 + 0 + 4 * h);
  f16x8 ca11 = ld8h(g_coef + rowbase1 + 8 + 4 * h);
  f16x8 ca12 = ld8h(g_coef + rowbase1 + 16 + 4 * h);
  f16x8 ca13 = ld8h(g_coef + rowbase1 + 24 + 4 * h);

  // coalesced stage of tile tt: 32 rows x 104B = 3328B = 208 16B-chunks.
  auto stage_tile = [&](int tt) {
    const uint4v* tb = (const uint4v*)(x + (size_t)(sbase + 32 * tt) * LDIM);
    char* db = (char*)&stage[warp][tt & 1][0];
    gload16(tb + lane, db + (size_t)lane * 16);
    gload16(tb + 64 + lane, db + 1024 + (size_t)lane * 16);
    gload16(tb + 128 + lane, db + 2048 + (size_t)lane * 16);
    if (lane < 16) gload16(tb + 192 + lane, db + 3072 + (size_t)lane * 16);
  };

  stage_tile(0);

#pragma unroll
  for (int t = 0; t < 4; ++t) {
    // drain this tile's DMA (issued a full tile ago, except t=0)
    asm volatile("s_waitcnt vmcnt(0)" ::: "memory");

    // ---- read own sample row from stage; pack to f16 pairs (x, x^2) ----
    unsigned xhu[13], squ[13];
    {
      const float2* srow = (const float2*)&stage[warp][t & 1][sl * LDIM];
#pragma unroll
      for (int j = 0; j < 13; ++j) {
        float2 v = srow[j];
        xhu[j] = pkrtz(v.x, v.y);
        squ[j] = pkrtz(v.x * v.x, v.y * v.y);
      }
    }

    // ---- issue next tile's DMA (consumed at top of t+1: full-tile cover) ----
    if (t < 3) stage_tile(t + 1);

    // ---- scatter transposes, SPLIT across halves: lanes sl and sl+32 hold
    //      the same sample row, so h0-lanes write XT while h1-lanes write SQT
    //      in the SAME ds_write. ----
    {
      unsigned short* Ts = h ? SQs : XTs;
#pragma unroll
      for (int c = 0; c < LDIM; ++c) {
        unsigned src = h ? squ[c >> 1] : xhu[c >> 1];
        unsigned v = (c & 1) ? (src >> 16) : (src & 0xffffu);
        Ts[(c * 32 + sl) ^ ((c & 7) << 3)] = (unsigned short)v;
      }
      Ts[(26 * 32 + sl) ^ ((26 & 7) << 3)] = h ? (unsigned short)0 : (unsigned short)0x3C00;
    }

    // ---- E GEMM: e0 (k 0..31), e1 (k 32..63); shared B fragments ----
    f32x16 e0 = {0,0,0,0,0,0,0,0,0,0,0,0,0,0,0,0};
    f32x16 e1 = {0,0,0,0,0,0,0,0,0,0,0,0,0,0,0,0};
    {
      uint4v b0 = {h ? squ[4] : squ[0], h ? squ[5] : squ[1],
                   h ? squ[6] : squ[2], h ? squ[7] : squ[3]};
      uint4v b1 = {h ? squ[12] : squ[8], h ? xhu[0] : squ[9],
                   h ? xhu[1] : squ[10], h ? xhu[2] : squ[11]};
      uint4v b2 = {h ? xhu[7] : xhu[3], h ? xhu[8] : xhu[4],
                   h ? xhu[9] : xhu[5], h ? xhu[10] : xhu[6]};
      uint4v b3 = {h ? 0u : xhu[11], h ? 0u : xhu[12],
                   h ? 0u : 0x3C003C00u, 0u};
      f16x8 fb0 = __builtin_bit_cast(f16x8, b0);
      f16x8 fb1 = __builtin_bit_cast(f16x8, b1);
      f16x8 fb2 = __builtin_bit_cast(f16x8, b2);
      f16x8 fb3 = __builtin_bit_cast(f16x8, b3);
      e0 = mfma16(ca00, fb0, e0);
      e1 = mfma16(ca10, fb0, e1);
      e0 = mfma16(ca01, fb1, e0);
      e1 = mfma16(ca11, fb1, e1);
      e0 = mfma16(ca02, fb2, e0);
      e1 = mfma16(ca12, fb2, e1);
      e0 = mfma16(ca03, fb3, e0);
      e1 = mfma16(ca13, fb3, e1);
    }

    // ---- softmax over all 64 k: in-lane tree over 32 regs + shfl_xor(32) ----
    float m8[8];
#pragma unroll
    for (int r = 0; r < 8; ++r)
      m8[r] = fmaxf(fmaxf(e0[r], e0[r + 8]), fmaxf(e1[r], e1[r + 8]));
#pragma unroll
    for (int d = 4; d > 0; d >>= 1)
#pragma unroll
      for (int r = 0; r < d; ++r) m8[r] = fmaxf(m8[r], m8[r + d]);
    const float M = fmaxf(m8[0], __shfl_xor(m8[0], 32));  // max over all 64 k
    const float mL = M * L2E;
#pragma unroll
    for (int r = 0; r < 16; ++r) {
      e0[r] = __builtin_amdgcn_exp2f(__builtin_fmaf(e0[r], L2E, -mL));
      e1[r] = __builtin_amdgcn_exp2f(__builtin_fmaf(e1[r], L2E, -mL));
    }
    float s8[8];
#pragma unroll
    for (int r = 0; r < 8; ++r)
      s8[r] = (e0[r] + e0[r + 8]) + (e1[r] + e1[r + 8]);
#pragma unroll
    for (int d = 4; d > 0; d >>= 1)
#pragma unroll
      for (int r = 0; r < d; ++r) s8[r] += s8[r + d];
    const float SS = s8[0] + __shfl_xor(s8[0], 32);       // sum over all 64 k
    const float scale = __builtin_amdgcn_rcpf(SS);
    llacc += M + __builtin_amdgcn_logf(SS) * LN2;         // counted by both lane-halves

    // ---- P^T scatter, both halves (D-row mapping m74/m101) ----
#pragma unroll
    for (int r = 0; r < 16; ++r) {
      const int row = (r & 3) + 8 * (r >> 2) + 4 * h;
      const int idx = (row * 32 + sl) ^ ((row & 7) << 3);
      _Float16 p0 = (_Float16)(e0[r] * scale);
      _Float16 p1 = (_Float16)(e1[r] * scale);
      PT0s[idx] = __builtin_bit_cast(unsigned short, p0);
      PT1s[idx] = __builtin_bit_cast(unsigned short, p1);
    }

    // ---- M GEMM: aX += P.X^T (col26 -> z), aQ += P.SQ^T, both halves ----
#pragma unroll
    for (int ks = 0; ks < 2; ++ks) {
      const int off = 8 * ks + 4 * h;
      const int swz = (sl & 7) << 2;
      f16x8 a0 = ld8h(&PT0d[(sl * 16 + off) ^ swz]);
      f16x8 a1 = ld8h(&PT1d[(sl * 16 + off) ^ swz]);
      f16x8 bx = ld8h(&XTd[(sl * 16 + off) ^ swz]);
      f16x8 bq = ld8h(&SQd[(sl * 16 + off) ^ swz]);
      aX0 = mfma16(a0, bx, aX0);
      aQ0 = mfma16(a0, bq, aQ0);
      aX1 = mfma16(a1, bx, aX1);
      aQ1 = mfma16(a1, bq, aQ1);
    }
  }

  // ---- epilogue: barrier (wave1 must finish reading its buffers BEFORE the
  //      overlay is written) -> wave0 stores -> barrier -> wave1 adds+stores ----
  __syncthreads();
  float* red = (float*)&pool[0];  // 13.6 KB overlay, now provably dead
  float llw = llacc * 0.5f;  // each sample counted by both lane-halves
#pragma unroll
  for (int d = 1; d < 64; d <<= 1) llw += __shfl_xor(llw, d, 64);
  if (warp == 0) {
#pragma unroll
    for (int r = 0; r < 16; ++r) {
      const int row = (r & 3) + 8 * (r >> 2) + 4 * h;
      if (sl < 26) {
        red[row * ACC_STRIDE + 1 + sl] = aX0[r];
        red[row * ACC_STRIDE + 27 + sl] = aQ0[r];
        red[(row + 32) * ACC_STRIDE + 1 + sl] = aX1[r];
        red[(row + 32) * ACC_STRIDE + 27 + sl] = aQ1[r];
      } else if (sl == 26) {
        red[row * ACC_STRIDE] = aX0[r];
        red[(row + 32) * ACC_STRIDE] = aX1[r];
      }
    }
    if (lane == 0) red[KDIM * ACC_STRIDE] = llw;
  }
  __syncthreads();
  if (warp == 1) {
    float* pb = g_partial + (size_t)blockIdx.x * PART_STRIDE;
#pragma unroll
    for (int r = 0; r < 16; ++r) {
      const int row = (r & 3) + 8 * (r >> 2) + 4 * h;
      if (sl < 26) {
        pb[row * ACC_STRIDE + 1 + sl] = red[row * ACC_STRIDE + 1 + sl] + aX0[r];
        pb[row * ACC_STRIDE + 27 + sl] = red[row * ACC_STRIDE + 27 + sl] + aQ0[r];
        pb[(row + 32) * ACC_STRIDE + 1 + sl] = red[(row + 32) * ACC_STRIDE + 1 + sl] + aX1[r];
        pb[(row + 32) * ACC_STRIDE + 27 + sl] = red[(row + 32) * ACC_STRIDE + 27 + sl] + aQ1[r];
      } else if (sl == 26) {
        pb[row * ACC_STRIDE] = red[row * ACC_STRIDE] + aX0[r];
        pb[(row + 32) * ACC_STRIDE] = red[(row + 32) * ACC_STRIDE] + aX1[r];
      }
    }
    if (lane == 0) pb[KDIM * ACC_STRIDE] = red[KDIM * ACC_STRIDE] + llw;
  }
}

// fold 1024 block-partials into 8 accumulator copies; the LAST block (ticket
// election, device-fenced — the R5-verified pattern) runs the finalize/M-step
// inline, saving one launch + gap per iteration.
__global__ void reduce_finalize() {
  const int i = blockIdx.x * 256 + threadIdx.x;
  const int cy = blockIdx.y;  // 8 chunks of 128 blocks
  if (i < ACC_N) {
    const float* p = g_partial + (size_t)cy * 128 * PART_STRIDE + i;
    float s = 0.f;
#pragma unroll 8
    for (int j = 0; j < 128; ++j) s += p[(size_t)j * PART_STRIDE];
    g_accum[cy * ACC_N + i] = s;
  }
  __threadfence();  // release g_accum stores before ticket
  __shared__ int elect;
  if (threadIdx.x == 0)
    elect = (atomicAdd(&g_ticket, 1) == RED_BLK * NCOPIES - 1) ? 1 : 0;
  __syncthreads();
  if (elect == 0) return;
  __threadfence();  // acquire all blocks' g_accum stores
  if (threadIdx.x == 0) g_ticket = 0;  // self-reset for next call
  const int k = threadIdx.x;
  if (k >= 64) return;
  float vals[ACC_STRIDE];
#pragma unroll
  for (int j = 0; j < ACC_STRIDE; ++j) vals[j] = 0.f;
  float llsum = 0.f;
  for (int cp = 0; cp < NCOPIES; ++cp) {
    const float* a = g_accum + cp * ACC_N;
#pragma unroll
    for (int j = 0; j < ACC_STRIDE; ++j) vals[j] += a[k * ACC_STRIDE + j];
    llsum += a[KDIM * ACC_STRIDE];
  }
  float z = vals[0];
  float wn = z * (1.0f / NSAMP);
  float wf = fmaxf(wn, WFLOOR);
  float S = wf;
#pragma unroll
  for (int d = 1; d < 64; d <<= 1) S += __shfl_xor(S, d, 64);
  const float sf = WFLOOR * KDIM;
  float a = (1.0f - sf) / (S - sf);
  float b = WFLOOR * (1.0f - a);
  float w = a * wf + b;
  g_w[k] = w;
  float zinv = 1.0f / z;
  float muk[LDIM], sgk[LDIM];
#pragma unroll
  for (int l = 0; l < LDIM; ++l) {
    float m = vals[1 + l] * zinv;
    float s2 = fmaxf(__builtin_fmaf(-m, m, vals[27 + l] * zinv), VFLOOR);
    muk[l] = m;
    sgk[l] = s2;
    g_mu[k * LDIM + l] = m;
    g_sig[k * LDIM + l] = s2;
  }
  if (k == 0) g_ll[0] = llsum;
  pack_row(k, w, muk, sgk, g_coef);
}

__global__ void writeout(float* __restrict__ out) {
  const int i = blockIdx.x * 256 + threadIdx.x;
  // out: w[64] | mu[64*26] | sigma[64*26*26] (diag) | ll[1]
  if (i < 64) {
    out[i] = g_w[i];
  } else if (i < 64 + KDIM * LDIM) {
    out[i] = g_mu[i - 64];
  } else if (i < 64 + KDIM * LDIM + KDIM * LDIM * LDIM) {
    int t = i - (64 + KDIM * LDIM);
    int k = t / (LDIM * LDIM);
    int r = t % (LDIM * LDIM);
    int ii = r / LDIM;
    int jj = r % LDIM;
    out[i] = (ii == jj) ? g_sig[k * LDIM + ii] : 0.f;
  } else if (i == 64 + KDIM * LDIM + KDIM * LDIM * LDIM) {
    out[i] = g_ll[0];
  }
}

extern "C" void kernel_launch(void* const* d_in, const int* in_sizes, int n_in,
                              void* d_out, int out_size, void* d_ws, size_t ws_size,
                              hipStream_t stream) {
  (void)in_sizes; (void)n_in; (void)d_ws; (void)ws_size; (void)out_size;
  const float* x   = (const float*)d_in[0];
  const float* w0  = (const float*)d_in[1];
  const float* mu0 = (const float*)d_in[2];
  const float* sg0 = (const float*)d_in[3];
  float* out = (float*)d_out;

  prep_coef<<<1, 64, 0, stream>>>(w0, mu0, sg0);
  for (int it = 0; it < NITER; ++it) {
    em_mfma<<<NBLK, 128, 0, stream>>>(x);
    reduce_finalize<<<dim3(RED_BLK, NCOPIES), 256, 0, stream>>>();
  }
  const int nout = 64 + KDIM * LDIM + KDIM * LDIM * LDIM + 1;  // 44993
  writeout<<<(nout + 255) / 256, 256, 0, stream>>>(out);
}

// Round 14
// 301.201 us; speedup vs baseline: 1.2172x; 1.2172x over previous
//
#include <hip/hip_runtime.h>
#include <math.h>

typedef _Float16 f16x8 __attribute__((ext_vector_type(8)));
typedef float f32x16 __attribute__((ext_vector_type(16)));
typedef unsigned int uint4v __attribute__((ext_vector_type(4)));

namespace {
constexpr int LDIM = 26;
constexpr int KDIM = 64;
constexpr int NSAMP = 262144;
constexpr int NITER = 8;
constexpr float WFLOOR = 1e-5f;
constexpr float VFLOOR = 1e-6f;
constexpr float LOG2PI_TERM = 47.784803726642976f;  // 26 * ln(2*pi)
constexpr float L2E = 1.44269504088896340736f;
constexpr float LN2 = 0.69314718055994530942f;

constexpr int ACC_STRIDE = 53;                       // z, px[26], pxx[26]
constexpr int ACC_N = KDIM * ACC_STRIDE + 1;         // 3393 (last = ll)
constexpr int NCOPIES = 8;
constexpr int WROW = 36;                             // dwords per coef row
constexpr int NBLK = 1024;                           // 2 indep waves/block; 256 samples/block
constexpr int PART_STRIDE = 3408;
}

// Static device storage (no dependence on the harness workspace; no fp atomics,
// no device fences).
__device__ float g_partial[NBLK * PART_STRIDE];                         // ~14 MB
__device__ float g_accum[NCOPIES * ACC_N];                              // 108 KB
__device__ float g_w[KDIM];
__device__ float g_mu[KDIM * LDIM];
__device__ float g_sig[KDIM * LDIM];
__device__ float g_ll[1];
__device__ __align__(16) unsigned g_coef[KDIM * WROW];                  // f16-pair coef rows

__device__ __forceinline__ unsigned pkrtz(float a, float b) {
  return __builtin_bit_cast(unsigned, __builtin_amdgcn_cvt_pkrtz(a, b));
}
__device__ __forceinline__ f16x8 ld8h(const unsigned* p) {
  uint4v v = *(const uint4v*)p;
  return __builtin_bit_cast(f16x8, v);
}
__device__ __forceinline__ f32x16 mfma16(f16x8 a, f16x8 b, f32x16 c) {
  return __builtin_amdgcn_mfma_f32_32x32x16_f16(a, b, c, 0, 0, 0);
}
// async global->LDS DMA, 16B per lane
__device__ __forceinline__ void gload16(const void* g, void* l) {
  __builtin_amdgcn_global_load_lds(
      (const __attribute__((address_space(1))) unsigned*)g,
      (__attribute__((address_space(3))) unsigned*)l, 16, 0, 0);
}

// Coef row k (f16 pairs, 36-dword rows): slots 0..25 = -0.5/sig, 26..51 = mu/sig,
// 52 = C, 53 = C - f16(C) (split constant), rest 0.
__device__ void pack_row(int k, float w, const float* mu, const float* sg, unsigned* wp) {
  float A[LDIM], Bv[LDIM];
  float logdet = 0.f, q = 0.f;
#pragma unroll
  for (int l = 0; l < LDIM; ++l) {
    float pr = 1.0f / sg[l];
    logdet += __logf(sg[l]);
    A[l] = -0.5f * pr;
    Bv[l] = mu[l] * pr;
    q = __builtin_fmaf(mu[l] * mu[l], pr, q);
  }
  float C = __logf(w) - 0.5f * (LOG2PI_TERM + logdet + q);
  float Chi = (float)__builtin_amdgcn_cvt_pkrtz(C, 0.0f)[0];
  float Clo = C - Chi;
  unsigned* row = wp + k * WROW;
#define CF(f) ((f) < 26 ? A[(f)] : (f) < 52 ? Bv[(f) - 26] : (f) == 52 ? C : (f) == 53 ? Clo : 0.0f)
#pragma unroll
  for (int D = 0; D < 32; ++D) row[D] = pkrtz(CF(2 * D), CF(2 * D + 1));
#undef CF
#pragma unroll
  for (int D = 32; D < 36; ++D) row[D] = 0u;
}

__global__ void prep_coef(const float* __restrict__ w0, const float* __restrict__ mu0,
                          const float* __restrict__ sig0) {
  const int k = threadIdx.x;  // 64 threads
  float wv = w0[k];
  float s = wv;
#pragma unroll
  for (int d = 1; d < 64; d <<= 1) s += __shfl_xor(s, d, 64);
  float w = wv / s;
  float mu[LDIM], sg[LDIM];
#pragma unroll
  for (int l = 0; l < LDIM; ++l) {
    mu[l] = mu0[k * LDIM + l];
    sg[l] = sig0[k * LDIM + l];
  }
  pack_row(k, w, mu, sg, g_coef);
}

// R7's verified structure: 2 INDEPENDENT waves per block (128 threads), each
// processing 4 tiles of 32 samples with private LDS buffers — ZERO barriers in
// the main loop. Each wave holds BOTH k-halves; softmax over all 64 components
// is in-lane tree + one shfl_xor(32).
// Epilogue (R5-verified coalesced store pattern, R7's join): barrier -> wave0
// stores accumulators into the LDS pool overlay -> barrier -> wave1 ADDS its
// own into the overlay (exclusive slots, plain LDS RMW) -> barrier -> both
// waves copy the merged 13.6KB to the block partial with fully-coalesced
// stores (avoids R4-observed 1.6x write amplification of scattered stores).
__global__ __launch_bounds__(128, 2) void em_mfma(const float* __restrict__ x) {
  // single pool hosting xtbuf+ptbuf, legally reusable as the reduce overlay
  __shared__ __align__(16) unsigned char pool[16384];
  __shared__ __align__(16) float stage[2][2][32 * LDIM];      // [warp][buf] 32x26 f32

  const int tid = threadIdx.x;
  const int lane = tid & 63;
  const int warp = tid >> 6;
  const int sl = lane & 31;
  const int h = lane >> 5;

  // layout: [warp][XT|SQT] at 0..8191, [warp][PT0|PT1] at 8192..16383
  unsigned short* XTs = (unsigned short*)&pool[warp * 4096];
  unsigned short* SQs = (unsigned short*)&pool[warp * 4096 + 2048];
  unsigned short* PT0s = (unsigned short*)&pool[8192 + warp * 4096];
  unsigned short* PT1s = (unsigned short*)&pool[8192 + warp * 4096 + 2048];
  const unsigned* XTd = (const unsigned*)XTs;
  const unsigned* SQd = (const unsigned*)SQs;
  const unsigned* PT0d = (const unsigned*)PT0s;
  const unsigned* PT1d = (const unsigned*)PT1s;

  f32x16 aX0 = {0,0,0,0,0,0,0,0,0,0,0,0,0,0,0,0};
  f32x16 aX1 = {0,0,0,0,0,0,0,0,0,0,0,0,0,0,0,0};
  f32x16 aQ0 = {0,0,0,0,0,0,0,0,0,0,0,0,0,0,0,0};
  f32x16 aQ1 = {0,0,0,0,0,0,0,0,0,0,0,0,0,0,0,0};
  float llacc = 0.f;

  const int sbase = blockIdx.x * 256 + warp * 128;
  const int rowbase0 = sl * WROW;
  const int rowbase1 = (32 + sl) * WROW;

  // ---- hoisted coefficient fragments for BOTH k-halves ----
  f16x8 ca00 = ld8h(g_coef + rowbase0 + 0 + 4 * h);
  f16x8 ca01 = ld8h(g_coef + rowbase0 + 8 + 4 * h);
  f16x8 ca02 = ld8h(g_coef + rowbase0 + 16 + 4 * h);
  f16x8 ca03 = ld8h(g_coef + rowbase0 + 24 + 4 * h);
  f16x8 ca10 = ld8h(g_coef + rowbase1 + 0 + 4 * h);
  f16x8 ca11 = ld8h(g_coef + rowbase1 + 8 + 4 * h);
  f16x8 ca12 = ld8h(g_coef + rowbase1 + 16 + 4 * h);
  f16x8 ca13 = ld8h(g_coef + rowbase1 + 24 + 4 * h);

  // coalesced stage of tile tt: 32 rows x 104B = 3328B = 208 16B-chunks.
  auto stage_tile = [&](int tt) {
    const uint4v* tb = (const uint4v*)(x + (size_t)(sbase + 32 * tt) * LDIM);
    char* db = (char*)&stage[warp][tt & 1][0];
    gload16(tb + lane, db + (size_t)lane * 16);
    gload16(tb + 64 + lane, db + 1024 + (size_t)lane * 16);
    gload16(tb + 128 + lane, db + 2048 + (size_t)lane * 16);
    if (lane < 16) gload16(tb + 192 + lane, db + 3072 + (size_t)lane * 16);
  };

  stage_tile(0);

#pragma unroll
  for (int t = 0; t < 4; ++t) {
    // drain this tile's DMA (issued a full tile ago, except t=0)
    asm volatile("s_waitcnt vmcnt(0)" ::: "memory");

    // ---- read own sample row from stage; pack to f16 pairs (x, x^2) ----
    unsigned xhu[13], squ[13];
    {
      const float2* srow = (const float2*)&stage[warp][t & 1][sl * LDIM];
#pragma unroll
      for (int j = 0; j < 13; ++j) {
        float2 v = srow[j];
        xhu[j] = pkrtz(v.x, v.y);
        squ[j] = pkrtz(v.x * v.x, v.y * v.y);
      }
    }

    // ---- issue next tile's DMA (consumed at top of t+1: full-tile cover) ----
    if (t < 3) stage_tile(t + 1);

    // ---- scatter transposes, SPLIT across halves: lanes sl and sl+32 hold
    //      the same sample row, so h0-lanes write XT while h1-lanes write SQT
    //      in the SAME ds_write. ----
    {
      unsigned short* Ts = h ? SQs : XTs;
#pragma unroll
      for (int c = 0; c < LDIM; ++c) {
        unsigned src = h ? squ[c >> 1] : xhu[c >> 1];
        unsigned v = (c & 1) ? (src >> 16) : (src & 0xffffu);
        Ts[(c * 32 + sl) ^ ((c & 7) << 3)] = (unsigned short)v;
      }
      Ts[(26 * 32 + sl) ^ ((26 & 7) << 3)] = h ? (unsigned short)0 : (unsigned short)0x3C00;
    }

    // ---- E GEMM: e0 (k 0..31), e1 (k 32..63); shared B fragments ----
    f32x16 e0 = {0,0,0,0,0,0,0,0,0,0,0,0,0,0,0,0};
    f32x16 e1 = {0,0,0,0,0,0,0,0,0,0,0,0,0,0,0,0};
    {
      uint4v b0 = {h ? squ[4] : squ[0], h ? squ[5] : squ[1],
                   h ? squ[6] : squ[2], h ? squ[7] : squ[3]};
      uint4v b1 = {h ? squ[12] : squ[8], h ? xhu[0] : squ[9],
                   h ? xhu[1] : squ[10], h ? xhu[2] : squ[11]};
      uint4v b2 = {h ? xhu[7] : xhu[3], h ? xhu[8] : xhu[4],
                   h ? xhu[9] : xhu[5], h ? xhu[10] : xhu[6]};
      uint4v b3 = {h ? 0u : xhu[11], h ? 0u : xhu[12],
                   h ? 0u : 0x3C003C00u, 0u};
      f16x8 fb0 = __builtin_bit_cast(f16x8, b0);
      f16x8 fb1 = __builtin_bit_cast(f16x8, b1);
      f16x8 fb2 = __builtin_bit_cast(f16x8, b2);
      f16x8 fb3 = __builtin_bit_cast(f16x8, b3);
      e0 = mfma16(ca00, fb0, e0);
      e1 = mfma16(ca10, fb0, e1);
      e0 = mfma16(ca01, fb1, e0);
      e1 = mfma16(ca11, fb1, e1);
      e0 = mfma16(ca02, fb2, e0);
      e1 = mfma16(ca12, fb2, e1);
      e0 = mfma16(ca03, fb3, e0);
      e1 = mfma16(ca13, fb3, e1);
    }

    // ---- softmax over all 64 k: in-lane tree over 32 regs + shfl_xor(32) ----
    float m8[8];
#pragma unroll
    for (int r = 0; r < 8; ++r)
      m8[r] = fmaxf(fmaxf(e0[r], e0[r + 8]), fmaxf(e1[r], e1[r + 8]));
#pragma unroll
    for (int d = 4; d > 0; d >>= 1)
#pragma unroll
      for (int r = 0; r < d; ++r) m8[r] = fmaxf(m8[r], m8[r + d]);
    const float M = fmaxf(m8[0], __shfl_xor(m8[0], 32));  // max over all 64 k
    const float mL = M * L2E;
#pragma unroll
    for (int r = 0; r < 16; ++r) {
      e0[r] = __builtin_amdgcn_exp2f(__builtin_fmaf(e0[r], L2E, -mL));
      e1[r] = __builtin_amdgcn_exp2f(__builtin_fmaf(e1[r], L2E, -mL));
    }
    float s8[8];
#pragma unroll
    for (int r = 0; r < 8; ++r)
      s8[r] = (e0[r] + e0[r + 8]) + (e1[r] + e1[r + 8]);
#pragma unroll
    for (int d = 4; d > 0; d >>= 1)
#pragma unroll
      for (int r = 0; r < d; ++r) s8[r] += s8[r + d];
    const float SS = s8[0] + __shfl_xor(s8[0], 32);       // sum over all 64 k
    const float scale = __builtin_amdgcn_rcpf(SS);
    llacc += M + __builtin_amdgcn_logf(SS) * LN2;         // counted by both lane-halves

    // ---- P^T scatter, both halves (D-row mapping m74/m101) ----
#pragma unroll
    for (int r = 0; r < 16; ++r) {
      const int row = (r & 3) + 8 * (r >> 2) + 4 * h;
      const int idx = (row * 32 + sl) ^ ((row & 7) << 3);
      _Float16 p0 = (_Float16)(e0[r] * scale);
      _Float16 p1 = (_Float16)(e1[r] * scale);
      PT0s[idx] = __builtin_bit_cast(unsigned short, p0);
      PT1s[idx] = __builtin_bit_cast(unsigned short, p1);
    }

    // ---- M GEMM: aX += P.X^T (col26 -> z), aQ += P.SQ^T, both halves ----
#pragma unroll
    for (int ks = 0; ks < 2; ++ks) {
      const int off = 8 * ks + 4 * h;
      const int swz = (sl & 7) << 2;
      f16x8 a0 = ld8h(&PT0d[(sl * 16 + off) ^ swz]);
      f16x8 a1 = ld8h(&PT1d[(sl * 16 + off) ^ swz]);
      f16x8 bx = ld8h(&XTd[(sl * 16 + off) ^ swz]);
      f16x8 bq = ld8h(&SQd[(sl * 16 + off) ^ swz]);
      aX0 = mfma16(a0, bx, aX0);
      aQ0 = mfma16(a0, bq, aQ0);
      aX1 = mfma16(a1, bx, aX1);
      aQ1 = mfma16(a1, bq, aQ1);
    }
  }

  // ---- epilogue: barrier (wave1 must finish reading its buffers BEFORE the
  //      overlay is written) -> wave0 stores -> barrier -> wave1 adds into the
  //      overlay -> barrier -> BOTH waves coalesced-copy to the partial ----
  __syncthreads();
  float* red = (float*)&pool[0];  // 13.6 KB overlay, now provably dead
  float llw = llacc * 0.5f;  // each sample counted by both lane-halves
#pragma unroll
  for (int d = 1; d < 64; d <<= 1) llw += __shfl_xor(llw, d, 64);
  if (warp == 0) {
#pragma unroll
    for (int r = 0; r < 16; ++r) {
      const int row = (r & 3) + 8 * (r >> 2) + 4 * h;
      if (sl < 26) {
        red[row * ACC_STRIDE + 1 + sl] = aX0[r];
        red[row * ACC_STRIDE + 27 + sl] = aQ0[r];
        red[(row + 32) * ACC_STRIDE + 1 + sl] = aX1[r];
        red[(row + 32) * ACC_STRIDE + 27 + sl] = aQ1[r];
      } else if (sl == 26) {
        red[row * ACC_STRIDE] = aX0[r];
        red[(row + 32) * ACC_STRIDE] = aX1[r];
      }
    }
    if (lane == 0) red[KDIM * ACC_STRIDE] = llw;
  }
  __syncthreads();
  if (warp == 1) {
#pragma unroll
    for (int r = 0; r < 16; ++r) {
      const int row = (r & 3) + 8 * (r >> 2) + 4 * h;
      if (sl < 26) {
        red[row * ACC_STRIDE + 1 + sl] += aX0[r];
        red[row * ACC_STRIDE + 27 + sl] += aQ0[r];
        red[(row + 32) * ACC_STRIDE + 1 + sl] += aX1[r];
        red[(row + 32) * ACC_STRIDE + 27 + sl] += aQ1[r];
      } else if (sl == 26) {
        red[row * ACC_STRIDE] += aX0[r];
        red[(row + 32) * ACC_STRIDE] += aX1[r];
      }
    }
    if (lane == 0) red[KDIM * ACC_STRIDE] += llw;
  }
  __syncthreads();
  {
    float* pb = g_partial + (size_t)blockIdx.x * PART_STRIDE;
    for (int i = tid; i < ACC_N; i += 128) pb[i] = red[i];
  }
}

// fold 1024 block-partials into 8 accumulator copies (plain stores, no atomics)
__global__ void reduce_partials() {
  const int i = blockIdx.x * 256 + threadIdx.x;
  if (i >= ACC_N) return;
  const int cy = blockIdx.y;  // 8 chunks of 128 blocks
  const float* p = g_partial + (size_t)cy * 128 * PART_STRIDE + i;
  float s = 0.f;
#pragma unroll 8
  for (int j = 0; j < 128; ++j) s += p[(size_t)j * PART_STRIDE];
  g_accum[cy * ACC_N + i] = s;
}

__global__ void finalize_k() {
  const int k = threadIdx.x;  // 64 threads
  float vals[ACC_STRIDE];
#pragma unroll
  for (int j = 0; j < ACC_STRIDE; ++j) vals[j] = 0.f;
  float llsum = 0.f;
  for (int cp = 0; cp < NCOPIES; ++cp) {
    const float* a = g_accum + cp * ACC_N;
#pragma unroll
    for (int j = 0; j < ACC_STRIDE; ++j) vals[j] += a[k * ACC_STRIDE + j];
    llsum += a[KDIM * ACC_STRIDE];
  }
  float z = vals[0];
  float wn = z * (1.0f / NSAMP);
  float wf = fmaxf(wn, WFLOOR);
  float S = wf;
#pragma unroll
  for (int d = 1; d < 64; d <<= 1) S += __shfl_xor(S, d, 64);
  const float sf = WFLOOR * KDIM;
  float a = (1.0f - sf) / (S - sf);
  float b = WFLOOR * (1.0f - a);
  float w = a * wf + b;
  g_w[k] = w;
  float zinv = 1.0f / z;
  float muk[LDIM], sgk[LDIM];
#pragma unroll
  for (int l = 0; l < LDIM; ++l) {
    float m = vals[1 + l] * zinv;
    float s2 = fmaxf(__builtin_fmaf(-m, m, vals[27 + l] * zinv), VFLOOR);
    muk[l] = m;
    sgk[l] = s2;
    g_mu[k * LDIM + l] = m;
    g_sig[k * LDIM + l] = s2;
  }
  if (k == 0) g_ll[0] = llsum;
  pack_row(k, w, muk, sgk, g_coef);
}

__global__ void writeout(float* __restrict__ out) {
  const int i = blockIdx.x * 256 + threadIdx.x;
  // out: w[64] | mu[64*26] | sigma[64*26*26] (diag) | ll[1]
  if (i < 64) {
    out[i] = g_w[i];
  } else if (i < 64 + KDIM * LDIM) {
    out[i] = g_mu[i - 64];
  } else if (i < 64 + KDIM * LDIM + KDIM * LDIM * LDIM) {
    int t = i - (64 + KDIM * LDIM);
    int k = t / (LDIM * LDIM);
    int r = t % (LDIM * LDIM);
    int ii = r / LDIM;
    int jj = r % LDIM;
    out[i] = (ii == jj) ? g_sig[k * LDIM + ii] : 0.f;
  } else if (i == 64 + KDIM * LDIM + KDIM * LDIM * LDIM) {
    out[i] = g_ll[0];
  }
}

extern "C" void kernel_launch(void* const* d_in, const int* in_sizes, int n_in,
                              void* d_out, int out_size, void* d_ws, size_t ws_size,
                              hipStream_t stream) {
  (void)in_sizes; (void)n_in; (void)d_ws; (void)ws_size; (void)out_size;
  const float* x   = (const float*)d_in[0];
  const float* w0  = (const float*)d_in[1];
  const float* mu0 = (const float*)d_in[2];
  const float* sg0 = (const float*)d_in[3];
  float* out = (float*)d_out;

  prep_coef<<<1, 64, 0, stream>>>(w0, mu0, sg0);
  for (int it = 0; it < NITER; ++it) {
    em_mfma<<<NBLK, 128, 0, stream>>>(x);
    reduce_partials<<<dim3(14, 8), 256, 0, stream>>>();
    finalize_k<<<1, 64, 0, stream>>>();
  }
  const int nout = 64 + KDIM * LDIM + KDIM * LDIM * LDIM + 1;  // 44993
  writeout<<<(nout + 255) / 256, 256, 0, stream>>>(out);
}